// Round 8
// baseline (922.741 us; speedup 1.0000x reference)
//
#include <hip/hip_runtime.h>
#include <math.h>

// Sizes: B=512, L=32, D=128, DT=128, S=63
#define SS 63
#define NEGF (-3.4028234663852886e+38f)

// d_out layout (floats): hidden(512*128) | thin(512*63*256) | trans(512*63) | lp | ent
#define OUT_THIN   65536
#define OUT_TRANS  8323072
#define OUT_LP     8355328
#define OUT_ENT    8387584

#define WC 14   // track_W rows per kq-group cached in LDS (4*14*512*4B = 112 KB)

__device__ __forceinline__ float sigf(float x) { return 1.0f / (1.0f + expf(-x)); }

// NOTE: param names must not collide with .x/.y/.z/.w member tokens (macro capture!)
#define FMA4(S, W, A) { (A).x = fmaf((S), (W).x, (A).x); (A).y = fmaf((S), (W).y, (A).y); \
                        (A).z = fmaf((S), (W).z, (A).z); (A).w = fmaf((S), (W).w, (A).w); }

// 256 blocks x 2 rows x 512 threads (8 waves) — L2-resident regime (13 MB fetch).
// 56 of 512 track_W K-rows (112 KB) live in LDS for the whole scan; the rest
// stream from L2 each step, shared across both rows in registers.
// Accumulation order identical to round 2 -> bit-identical output (absmax 0.015625).
// Refuted/forbidden (evidence): K-loop rotation (r6: +bank conflicts, no L2 gain);
// long-lived register W-cache (r4: hipcc spill -> GBs scratch); launch_bounds
// waves/EU tightening (r5: VGPR cap -> spill -> 338 MB fetch).
// Verified identities: s1=thin[t-1], s2=thin[t-2]; compose st1/st2 are zero rows ->
// comp needs only K-rows 128..255 and the ci/co/cg columns (packed 384).
__global__ __launch_bounds__(512, 2) void spinn_kernel(
    const int* __restrict__ messages,
    const float* __restrict__ embedding,
    const float* __restrict__ track_W,
    const float* __restrict__ track_b,
    const float* __restrict__ trans_W,
    const float* __restrict__ trans_b,
    const float* __restrict__ comp_W,
    const float* __restrict__ comp_b,
    const float* __restrict__ ln_g,
    const float* __restrict__ ln_b,
    float* __restrict__ out)
{
  __shared__ __align__(16) float wS[4][WC][512];    // cached track_W rows (112 KB)
  __shared__ __align__(16) float gS[2][4][512];     // track partials [row][kq][col]
  __shared__ __align__(16) float compS[2][4][384];  // comp partials [row][kq][packed ci|co|cg]
  __shared__ __align__(16) float thinL[2][2][128];  // rolling thin[t-1], thin[t-2] first halves
  __shared__ __align__(16) float topS[2][128];      // emb[msg[bp]] first half
  __shared__ __align__(16) float e1S[2][128];       // emb[msg[bp]] second half
  __shared__ __align__(16) float hS[2][128];
  __shared__ __align__(16) float cS[2][128];
  __shared__ float tbS[512];                        // track_b
  __shared__ float cbS[384];                        // comp_b packed [ci|co|cg]
  __shared__ float lgS[256], lbS[256];
  __shared__ float twS[256];                        // trans_W
  __shared__ float twbS[2];                         // trans_b
  __shared__ int   msgS[2][32];
  __shared__ int   scalS[2][8];                     // 0:qi 1:bp 2:us 3:len 4:is_r
  __shared__ double redP[8][2];                     // prologue LN stats

  const int tid = (int)threadIdx.x;
  const int b0 = (int)blockIdx.x * 2;

  // ---- per-thread invariants ----
  // phase B (track GEMV): kq in [0,4) picks 128 K-rows (= x segment); col4: 4 cols
  const int kq   = tid >> 7;
  const int col4 = (tid & 127) << 2;
  const float* const wpB = track_W + (size_t)(kq << 7) * 512 + col4;
  // phase D (comp GEMV): 384 threads (tid in [128,512)): g=gate, kqd: 32 K-rows
  const int du = tid - 128;
  int kqd = 0, pcol4 = 0, real4 = 0, gD = 0;
  if (du >= 0) {
    gD = du >> 7;                               // 0:ci 1:co 2:cg
    const int w7 = du & 127;
    kqd = w7 >> 5;                              // [0,4) -> 32 K-rows each
    pcol4 = (gD << 7) + ((w7 & 31) << 2);       // packed col [0,384)
    const int colbase = (gD == 0) ? 0 : ((gD == 1) ? 384 : 512);
    real4 = colbase + ((w7 & 31) << 2);
  }
  const float* const wpD = comp_W + (size_t)(128 + (kqd << 5)) * 640 + real4;

  // ---- P0: stage constants + W cache ----
  if (tid < 64) msgS[tid >> 5][tid & 31] = messages[(b0 + (tid >> 5)) * 32 + (tid & 31)];
  if (tid < 2) twbS[tid] = trans_b[tid];
  tbS[tid] = track_b[tid];
  if (tid < 384) {
    const int g = tid >> 7;
    const int off = (g == 0) ? 0 : ((g == 1) ? 384 : 512);
    cbS[tid] = comp_b[off + (tid & 127)];
  }
  if (tid < 256) {
    lgS[tid] = ln_g[tid]; lbS[tid] = ln_b[tid]; twS[tid] = trans_W[tid];
    hS[tid >> 7][tid & 127] = 0.0f; cS[tid >> 7][tid & 127] = 0.0f;
  }
  // stage first WC rows of this thread's kq-group (same mapping as B reads)
  #pragma unroll
  for (int r = 0; r < WC; ++r)
    *(float4*)&wS[kq][r][col4] = *(const float4*)(wpB + (size_t)r * 512);
  __syncthreads();

  // ---- P1: scalar init + topS for t=2 ----
  if (tid < 2) {
    const int r = tid;
    int len = 32;
    for (int i = 0; i < 32; ++i) if (msgS[r][i] == 0) { len = i + 1; break; }
    scalS[r][0] = 1; scalS[r][1] = 2; scalS[r][2] = len - 2; scalS[r][3] = len; scalS[r][4] = 0;
    const int bb = b0 + r;
    #pragma unroll
    for (int s = 0; s < 2; ++s) {
      const int done = (s >= 2 * len - 1);
      out[OUT_TRANS + bb * SS + s] = done ? 2.0f : 0.0f;
      out[OUT_LP + bb * SS + s] = 0.0f;
      out[OUT_ENT + bb * SS + s] = 0.0f;
    }
  }
  if (tid >= 256) {
    const int u = tid - 256;
    if (u < 256) topS[u >> 7][u & 127] = embedding[(size_t)msgS[u >> 7][2] * 256 + (u & 127)];
  }
  __syncthreads();

  // ---- P2: thin[0], thin[1] = LN(emb[msg[0/1]]) (512 threads: s=tid>>8) ----
  {
    const int s = tid >> 8, row = (tid >> 7) & 1, c = tid & 127;
    const int tok = msgS[row][s];
    const float v0 = embedding[(size_t)tok * 256 + c];
    const float v1 = embedding[(size_t)tok * 256 + 128 + c];
    double sm = (double)v0 + (double)v1;
    double sq = (double)v0 * v0 + (double)v1 * v1;
    #pragma unroll
    for (int off = 32; off; off >>= 1) { sm += __shfl_down(sm, off); sq += __shfl_down(sq, off); }
    if ((tid & 63) == 0) { redP[tid >> 6][0] = sm; redP[tid >> 6][1] = sq; }
    __syncthreads();
    const int wb = (tid >> 7) << 1;
    const double mu_d = (redP[wb][0] + redP[wb + 1][0]) * (1.0 / 256.0);
    const double ex2  = (redP[wb][1] + redP[wb + 1][1]) * (1.0 / 256.0);
    const float muf = (float)mu_d;
    const float inv = 1.0f / sqrtf((float)(ex2 - mu_d * mu_d) + 1e-5f);
    const float o0 = (v0 - muf) * inv * lgS[c] + lbS[c];
    const float o1 = (v1 - muf) * inv * lgS[128 + c] + lbS[128 + c];
    float* tp = out + OUT_THIN + ((size_t)(b0 + row) * SS + s) * 256;
    tp[c] = o0; tp[128 + c] = o1;
    thinL[row][s][c] = o0;
    __syncthreads();
  }

  // ---------------- scan: t = 2 .. 62 ----------------
  for (int t = 2; t < SS; ++t) {
    // B: gates partials (all 8 waves); K-rows 0..13 from LDS, 14..127 streamed from L2
    {
      const float *xb0, *xb1;
      if (kq == 0)      { xb0 = topS[0];               xb1 = topS[1]; }
      else if (kq == 1) { xb0 = thinL[0][(t + 1) & 1]; xb1 = thinL[1][(t + 1) & 1]; }
      else if (kq == 2) { xb0 = thinL[0][t & 1];       xb1 = thinL[1][t & 1]; }
      else              { xb0 = hS[0];                 xb1 = hS[1]; }
      float4 a0 = {0.f, 0.f, 0.f, 0.f}, a1 = {0.f, 0.f, 0.f, 0.f};
      // cached K-row quads 0..2 (rows 0..11), LDS
      #pragma unroll
      for (int k4 = 0; k4 < 3; ++k4) {
        const float4 x0 = *(const float4*)&xb0[k4 << 2];
        const float4 x1 = *(const float4*)&xb1[k4 << 2];
        float4 w;
        w = *(const float4*)&wS[kq][k4 * 4 + 0][col4]; FMA4(x0.x, w, a0); FMA4(x1.x, w, a1);
        w = *(const float4*)&wS[kq][k4 * 4 + 1][col4]; FMA4(x0.y, w, a0); FMA4(x1.y, w, a1);
        w = *(const float4*)&wS[kq][k4 * 4 + 2][col4]; FMA4(x0.z, w, a0); FMA4(x1.z, w, a1);
        w = *(const float4*)&wS[kq][k4 * 4 + 3][col4]; FMA4(x0.w, w, a0); FMA4(x1.w, w, a1);
      }
      // mixed quad 3: rows 12,13 LDS; rows 14,15 streamed
      {
        const float4 x0 = *(const float4*)&xb0[12];
        const float4 x1 = *(const float4*)&xb1[12];
        float4 w;
        w = *(const float4*)&wS[kq][12][col4];        FMA4(x0.x, w, a0); FMA4(x1.x, w, a1);
        w = *(const float4*)&wS[kq][13][col4];        FMA4(x0.y, w, a0); FMA4(x1.y, w, a1);
        w = *(const float4*)(wpB + (size_t)14 * 512); FMA4(x0.z, w, a0); FMA4(x1.z, w, a1);
        w = *(const float4*)(wpB + (size_t)15 * 512); FMA4(x0.w, w, a0); FMA4(x1.w, w, a1);
      }
      // streamed K-row quads 4..31 (rows 16..127)
      #pragma unroll 14
      for (int k4 = 4; k4 < 32; ++k4) {
        const float4 x0 = *(const float4*)&xb0[k4 << 2];
        const float4 x1 = *(const float4*)&xb1[k4 << 2];
        float4 w;
        w = *(const float4*)(wpB + (size_t)(k4 * 4 + 0) * 512); FMA4(x0.x, w, a0); FMA4(x1.x, w, a1);
        w = *(const float4*)(wpB + (size_t)(k4 * 4 + 1) * 512); FMA4(x0.y, w, a0); FMA4(x1.y, w, a1);
        w = *(const float4*)(wpB + (size_t)(k4 * 4 + 2) * 512); FMA4(x0.z, w, a0); FMA4(x1.z, w, a1);
        w = *(const float4*)(wpB + (size_t)(k4 * 4 + 3) * 512); FMA4(x0.w, w, a0); FMA4(x1.w, w, a1);
      }
      *(float4*)&gS[0][kq][col4] = a0;
      *(float4*)&gS[1][kq][col4] = a1;
    }
    __syncthreads();

    // C: LSTM + logits + decision (one wave per row, 2 cells/lane)
    if (tid < 128) {
      const int row = tid >> 6, l = tid & 63;
      double p0 = 0.0, p1 = 0.0;
      #pragma unroll
      for (int j = 0; j < 2; ++j) {
        const int cell = l + (j << 6);
        float gi = tbS[cell], gf = tbS[128 + cell], go = tbS[256 + cell], gg = tbS[384 + cell];
        #pragma unroll
        for (int k = 0; k < 4; ++k) {
          gi += gS[row][k][cell];
          gf += gS[row][k][128 + cell];
          go += gS[row][k][256 + cell];
          gg += gS[row][k][384 + cell];
        }
        const float cv = sigf(gf) * cS[row][cell] + sigf(gi) * tanhf(gg);
        const float hv = sigf(go) * tanhf(cv);
        cS[row][cell] = cv; hS[row][cell] = hv;
        p0 += (double)hv * (double)twS[2 * cell];
        p1 += (double)hv * (double)twS[2 * cell + 1];
      }
      #pragma unroll
      for (int off = 32; off; off >>= 1) { p0 += __shfl_down(p0, off); p1 += __shfl_down(p1, off); }
      if (l == 0) {
        const int qi0 = scalS[row][0], bp0 = scalS[row][1], us = scalS[row][2], len = scalS[row][3];
        float l0 = (float)p0 + twbS[0];
        float l1 = (float)p1 + twbS[1];
        if (us == 0)  l0 += NEGF;
        if (qi0 <= 0) l1 += NEGF;
        const int trans = (l1 > l0) ? 1 : 0;
        const float m = fmaxf(l0, l1);
        const float sh0 = l0 - m, sh1 = l1 - m;
        const float lse = logf(expf(sh0) + expf(sh1));
        const float lp0 = sh0 - lse, lp1 = sh1 - lse;
        const float logp = trans ? lp1 : lp0;
        const float pe0 = expf(lp0), pe1 = expf(lp1);
        const float ent = -((pe0 > 0.f ? pe0 * lp0 : 0.f) + (pe1 > 0.f ? pe1 * lp1 : 0.f));
        const int is_s = trans ? 0 : 1;
        const int is_r = trans;
        int qi2 = qi0 + is_s - is_r; qi2 = (qi2 < -1) ? -1 : ((qi2 > 31) ? 31 : qi2);
        int bp2 = bp0 + is_s; if (bp2 > 31) bp2 = 31;
        scalS[row][0] = qi2; scalS[row][1] = bp2; scalS[row][2] = us - is_s; scalS[row][4] = is_r;
        const int bb = b0 + row;
        const int done = (t >= 2 * len - 1);
        out[OUT_TRANS + bb * SS + t] = done ? 2.0f : (float)trans;
        out[OUT_LP + bb * SS + t]    = done ? 0.0f : logp;
        out[OUT_ENT + bb * SS + t]   = done ? 0.0f : ent;
      }
    }
    __syncthreads();

    // D: embedding prefetch (tid<128) || comp matvec (tid>=128, only if some row reduced)
    if (du < 0) {
      const int row = tid >> 6, c2 = (tid & 63) << 1;
      const int tok = msgS[row][scalS[row][1]];
      const float2 ea = *(const float2*)&embedding[(size_t)tok * 256 + c2];
      const float2 eb = *(const float2*)&embedding[(size_t)tok * 256 + 128 + c2];
      *(float2*)&topS[row][c2] = ea;
      *(float2*)&e1S[row][c2] = eb;
    } else if (scalS[0][4] | scalS[1][4]) {
      float4 a0 = {0.f, 0.f, 0.f, 0.f}, a1 = {0.f, 0.f, 0.f, 0.f};
      const float* hp0 = &hS[0][kqd << 5];
      const float* hp1 = &hS[1][kqd << 5];
      #pragma unroll 4
      for (int q = 0; q < 8; ++q) {
        const float4 h0 = *(const float4*)&hp0[q << 2];
        const float4 h1 = *(const float4*)&hp1[q << 2];
        float4 w;
        w = *(const float4*)(wpD + (size_t)(q * 4 + 0) * 640); FMA4(h0.x, w, a0); FMA4(h1.x, w, a1);
        w = *(const float4*)(wpD + (size_t)(q * 4 + 1) * 640); FMA4(h0.y, w, a0); FMA4(h1.y, w, a1);
        w = *(const float4*)(wpD + (size_t)(q * 4 + 2) * 640); FMA4(h0.z, w, a0); FMA4(h1.z, w, a1);
        w = *(const float4*)(wpD + (size_t)(q * 4 + 3) * 640); FMA4(h0.w, w, a0); FMA4(h1.w, w, a1);
      }
      *(float4*)&compS[0][kqd][pcol4] = a0;
      *(float4*)&compS[1][kqd][pcol4] = a1;
    }
    __syncthreads();

    // E: compose/shift + LN, one wave per row, lanes cover c=l and c=l+64
    if (tid < 128) {
      const int row = tid >> 6, l = tid & 63;
      float va0, va1, vb0, vb1;
      if (scalS[row][4]) {
        #pragma unroll
        for (int half = 0; half < 2; ++half) {
          const int c = l + (half << 6);
          float ci = cbS[c], co = cbS[128 + c], cg = cbS[256 + c];
          #pragma unroll
          for (int k = 0; k < 4; ++k) {
            ci += compS[row][k][c];
            co += compS[row][k][128 + c];
            cg += compS[row][k][256 + c];
          }
          const float cc = sigf(ci) * tanhf(cg);
          const float ch = sigf(co) * cc;
          if (half == 0) { va0 = ch; va1 = cc; } else { vb0 = ch; vb1 = cc; }
        }
      } else {
        va0 = topS[row][l];      va1 = e1S[row][l];
        vb0 = topS[row][l + 64]; vb1 = e1S[row][l + 64];
      }
      double sm = (double)va0 + (double)va1 + (double)vb0 + (double)vb1;
      double sq = (double)va0 * va0 + (double)va1 * va1 + (double)vb0 * vb0 + (double)vb1 * vb1;
      #pragma unroll
      for (int off = 32; off; off >>= 1) { sm += __shfl_xor(sm, off); sq += __shfl_xor(sq, off); }
      const double mu_d = sm * (1.0 / 256.0);
      const double ex2  = sq * (1.0 / 256.0);
      const float muf = (float)mu_d;
      const float inv = 1.0f / sqrtf((float)(ex2 - mu_d * mu_d) + 1e-5f);
      float* tp = out + OUT_THIN + ((size_t)(b0 + row) * SS + t) * 256;
      const float oa0 = (va0 - muf) * inv * lgS[l] + lbS[l];
      const float ob0 = (vb0 - muf) * inv * lgS[l + 64] + lbS[l + 64];
      tp[l]        = oa0;
      tp[l + 64]   = ob0;
      tp[128 + l]      = (va1 - muf) * inv * lgS[128 + l] + lbS[128 + l];
      tp[128 + l + 64] = (vb1 - muf) * inv * lgS[128 + l + 64] + lbS[128 + l + 64];
      thinL[row][t & 1][l]      = oa0;
      thinL[row][t & 1][l + 64] = ob0;
    }
    __syncthreads();
  }

  // epilogue: hidden = thin[2*len-2][:128]
  if (tid < 256) {
    const int row = tid >> 7, c = tid & 127;
    const int len = scalS[row][3];
    const int bb = b0 + row;
    out[(size_t)bb * 128 + c] = out[OUT_THIN + ((size_t)bb * SS + (2 * len - 2)) * 256 + c];
  }
}

extern "C" void kernel_launch(void* const* d_in, const int* in_sizes, int n_in,
                              void* d_out, int out_size, void* d_ws, size_t ws_size,
                              hipStream_t stream) {
  const int*   messages  = (const int*)d_in[0];
  const float* embedding = (const float*)d_in[1];
  const float* track_W   = (const float*)d_in[2];
  const float* track_b   = (const float*)d_in[3];
  const float* trans_W   = (const float*)d_in[4];
  const float* trans_b   = (const float*)d_in[5];
  const float* comp_W    = (const float*)d_in[6];
  const float* comp_b    = (const float*)d_in[7];
  const float* ln_g      = (const float*)d_in[8];
  const float* ln_b      = (const float*)d_in[9];
  float* out = (float*)d_out;
  (void)in_sizes; (void)n_in; (void)out_size; (void)d_ws; (void)ws_size;

  spinn_kernel<<<dim3(256), dim3(512), 0, stream>>>(
      messages, embedding, track_W, track_b, trans_W, trans_b,
      comp_W, comp_b, ln_g, ln_b, out);
}

// Round 9
// 719.888 us; speedup vs baseline: 1.2818x; 1.2818x over previous
//
#include <hip/hip_runtime.h>
#include <math.h>

// Sizes: B=512, L=32, D=128, DT=128, S=63
#define SS 63
#define NEGF (-3.4028234663852886e+38f)

// d_out layout (floats): hidden(512*128) | thin(512*63*256) | trans(512*63) | lp | ent
#define OUT_THIN   65536
#define OUT_TRANS  8323072
#define OUT_LP     8355328
#define OUT_ENT    8387584

#define WC 12   // track_W rows per kq-group cached in LDS (4*12*512*4B = 96 KB)

__device__ __forceinline__ float sigf(float x) { return 1.0f / (1.0f + expf(-x)); }

// NOTE: param names must not collide with .x/.y/.z/.w member tokens (macro capture!)
#define FMA4(S, W, A) { (A).x = fmaf((S), (W).x, (A).x); (A).y = fmaf((S), (W).y, (A).y); \
                        (A).z = fmaf((S), (W).z, (A).z); (A).w = fmaf((S), (W).w, (A).w); }

// 256 blocks x 2 rows x 512 threads (8 waves) — exact round-7 structure (666 us)
// plus a rolling register prefetch: weight quads 3..5 issued at phase-D head and
// 6..8 at phase-E head for the NEXT step, so the L2 port streams during the
// C/D/E window instead of idling. Consumption order in B unchanged -> output
// bit-identical to r7 (absmax must be exactly 0.015625).
// Refuted/forbidden (evidence): stream unroll >8 (r8: -28% — load bursts stall);
// WC=14 (r8 confound, <=1.7% upside); K-loop rotation (r6); long-lived register
// W-cache across whole loop (r4 spill); launch_bounds waves/EU cap (r5 spill).
// Verified identities: s1=thin[t-1], s2=thin[t-2]; compose st1/st2 are zero rows ->
// comp needs only K-rows 128..255 and the ci/co/cg columns (packed 384).
__global__ __launch_bounds__(512, 2) void spinn_kernel(
    const int* __restrict__ messages,
    const float* __restrict__ embedding,
    const float* __restrict__ track_W,
    const float* __restrict__ track_b,
    const float* __restrict__ trans_W,
    const float* __restrict__ trans_b,
    const float* __restrict__ comp_W,
    const float* __restrict__ comp_b,
    const float* __restrict__ ln_g,
    const float* __restrict__ ln_b,
    float* __restrict__ out)
{
  __shared__ __align__(16) float wS[4][WC][512];    // cached track_W rows (96 KB)
  __shared__ __align__(16) float gS[2][4][512];     // track partials [row][kq][col]
  __shared__ __align__(16) float compS[2][4][384];  // comp partials [row][kq][packed ci|co|cg]
  __shared__ __align__(16) float thinL[2][2][128];  // rolling thin[t-1], thin[t-2] first halves
  __shared__ __align__(16) float topS[2][128];      // emb[msg[bp]] first half
  __shared__ __align__(16) float e1S[2][128];       // emb[msg[bp]] second half
  __shared__ __align__(16) float hS[2][128];
  __shared__ __align__(16) float cS[2][128];
  __shared__ float tbS[512];                        // track_b
  __shared__ float cbS[384];                        // comp_b packed [ci|co|cg]
  __shared__ float lgS[256], lbS[256];
  __shared__ float twS[256];                        // trans_W
  __shared__ float twbS[2];                         // trans_b
  __shared__ int   msgS[2][32];
  __shared__ int   scalS[2][8];                     // 0:qi 1:bp 2:us 3:len 4:is_r
  __shared__ double redP[8][2];                     // prologue LN stats

  const int tid = (int)threadIdx.x;
  const int b0 = (int)blockIdx.x * 2;

  // ---- per-thread invariants ----
  const int kq   = tid >> 7;
  const int col4 = (tid & 127) << 2;
  const float* const wpB = track_W + (size_t)(kq << 7) * 512 + col4;
  const int du = tid - 128;
  int kqd = 0, pcol4 = 0, real4 = 0, gD = 0;
  if (du >= 0) {
    gD = du >> 7;                               // 0:ci 1:co 2:cg
    const int w7 = du & 127;
    kqd = w7 >> 5;                              // [0,4) -> 32 K-rows each
    pcol4 = (gD << 7) + ((w7 & 31) << 2);       // packed col [0,384)
    const int colbase = (gD == 0) ? 0 : ((gD == 1) ? 384 : 512);
    real4 = colbase + ((w7 & 31) << 2);
  }
  const float* const wpD = comp_W + (size_t)(128 + (kqd << 5)) * 640 + real4;

  // ---- P0: stage constants + W cache ----
  if (tid < 64) msgS[tid >> 5][tid & 31] = messages[(b0 + (tid >> 5)) * 32 + (tid & 31)];
  if (tid < 2) twbS[tid] = trans_b[tid];
  tbS[tid] = track_b[tid];
  if (tid < 384) {
    const int g = tid >> 7;
    const int off = (g == 0) ? 0 : ((g == 1) ? 384 : 512);
    cbS[tid] = comp_b[off + (tid & 127)];
  }
  if (tid < 256) {
    lgS[tid] = ln_g[tid]; lbS[tid] = ln_b[tid]; twS[tid] = trans_W[tid];
    hS[tid >> 7][tid & 127] = 0.0f; cS[tid >> 7][tid & 127] = 0.0f;
  }
  #pragma unroll
  for (int r = 0; r < WC; ++r)
    *(float4*)&wS[kq][r][col4] = *(const float4*)(wpB + (size_t)r * 512);
  __syncthreads();

  // ---- P1: scalar init + topS for t=2 ----
  if (tid < 2) {
    const int r = tid;
    int len = 32;
    for (int i = 0; i < 32; ++i) if (msgS[r][i] == 0) { len = i + 1; break; }
    scalS[r][0] = 1; scalS[r][1] = 2; scalS[r][2] = len - 2; scalS[r][3] = len; scalS[r][4] = 0;
    const int bb = b0 + r;
    #pragma unroll
    for (int s = 0; s < 2; ++s) {
      const int done = (s >= 2 * len - 1);
      out[OUT_TRANS + bb * SS + s] = done ? 2.0f : 0.0f;
      out[OUT_LP + bb * SS + s] = 0.0f;
      out[OUT_ENT + bb * SS + s] = 0.0f;
    }
  }
  if (tid >= 256) {
    const int u = tid - 256;
    if (u < 256) topS[u >> 7][u & 127] = embedding[(size_t)msgS[u >> 7][2] * 256 + (u & 127)];
  }
  __syncthreads();

  // ---- P2: thin[0], thin[1] = LN(emb[msg[0/1]]) ----
  {
    const int s = tid >> 8, row = (tid >> 7) & 1, c = tid & 127;
    const int tok = msgS[row][s];
    const float v0 = embedding[(size_t)tok * 256 + c];
    const float v1 = embedding[(size_t)tok * 256 + 128 + c];
    double sm = (double)v0 + (double)v1;
    double sq = (double)v0 * v0 + (double)v1 * v1;
    #pragma unroll
    for (int off = 32; off; off >>= 1) { sm += __shfl_down(sm, off); sq += __shfl_down(sq, off); }
    if ((tid & 63) == 0) { redP[tid >> 6][0] = sm; redP[tid >> 6][1] = sq; }
    __syncthreads();
    const int wb = (tid >> 7) << 1;
    const double mu_d = (redP[wb][0] + redP[wb + 1][0]) * (1.0 / 256.0);
    const double ex2  = (redP[wb][1] + redP[wb + 1][1]) * (1.0 / 256.0);
    const float muf = (float)mu_d;
    const float inv = 1.0f / sqrtf((float)(ex2 - mu_d * mu_d) + 1e-5f);
    const float o0 = (v0 - muf) * inv * lgS[c] + lbS[c];
    const float o1 = (v1 - muf) * inv * lgS[128 + c] + lbS[128 + c];
    float* tp = out + OUT_THIN + ((size_t)(b0 + row) * SS + s) * 256;
    tp[c] = o0; tp[128 + c] = o1;
    thinL[row][s][c] = o0;
    __syncthreads();
  }

  // ---- rolling prefetch registers (quads 3..5 from D, 6..8 from E) ----
  float4 pfd[3][4], pfe[3][4];
  #pragma unroll
  for (int q = 0; q < 3; ++q)
    #pragma unroll
    for (int r = 0; r < 4; ++r) {
      pfd[q][r] = *(const float4*)(wpB + (size_t)((q + 3) * 4 + r) * 512);
      pfe[q][r] = *(const float4*)(wpB + (size_t)((q + 6) * 4 + r) * 512);
    }

  // ---------------- scan: t = 2 .. 62 ----------------
  for (int t = 2; t < SS; ++t) {
    // B: gates partials. K-rows 0..11 LDS, 12..35 prefetched regs, 36..127 streamed
    {
      const float *xb0, *xb1;
      if (kq == 0)      { xb0 = topS[0];               xb1 = topS[1]; }
      else if (kq == 1) { xb0 = thinL[0][(t + 1) & 1]; xb1 = thinL[1][(t + 1) & 1]; }
      else if (kq == 2) { xb0 = thinL[0][t & 1];       xb1 = thinL[1][t & 1]; }
      else              { xb0 = hS[0];                 xb1 = hS[1]; }
      float4 a0 = {0.f, 0.f, 0.f, 0.f}, a1 = {0.f, 0.f, 0.f, 0.f};
      // cached K-row quads 0..2 (LDS)
      #pragma unroll
      for (int k4 = 0; k4 < 3; ++k4) {
        const float4 x0 = *(const float4*)&xb0[k4 << 2];
        const float4 x1 = *(const float4*)&xb1[k4 << 2];
        float4 w;
        w = *(const float4*)&wS[kq][k4 * 4 + 0][col4]; FMA4(x0.x, w, a0); FMA4(x1.x, w, a1);
        w = *(const float4*)&wS[kq][k4 * 4 + 1][col4]; FMA4(x0.y, w, a0); FMA4(x1.y, w, a1);
        w = *(const float4*)&wS[kq][k4 * 4 + 2][col4]; FMA4(x0.z, w, a0); FMA4(x1.z, w, a1);
        w = *(const float4*)&wS[kq][k4 * 4 + 3][col4]; FMA4(x0.w, w, a0); FMA4(x1.w, w, a1);
      }
      // prefetched quads 3..5 (issued in previous step's D phase)
      #pragma unroll
      for (int q = 0; q < 3; ++q) {
        const float4 x0 = *(const float4*)&xb0[(q + 3) << 2];
        const float4 x1 = *(const float4*)&xb1[(q + 3) << 2];
        FMA4(x0.x, pfd[q][0], a0); FMA4(x1.x, pfd[q][0], a1);
        FMA4(x0.y, pfd[q][1], a0); FMA4(x1.y, pfd[q][1], a1);
        FMA4(x0.z, pfd[q][2], a0); FMA4(x1.z, pfd[q][2], a1);
        FMA4(x0.w, pfd[q][3], a0); FMA4(x1.w, pfd[q][3], a1);
      }
      // prefetched quads 6..8 (issued in previous step's E phase)
      #pragma unroll
      for (int q = 0; q < 3; ++q) {
        const float4 x0 = *(const float4*)&xb0[(q + 6) << 2];
        const float4 x1 = *(const float4*)&xb1[(q + 6) << 2];
        FMA4(x0.x, pfe[q][0], a0); FMA4(x1.x, pfe[q][0], a1);
        FMA4(x0.y, pfe[q][1], a0); FMA4(x1.y, pfe[q][1], a1);
        FMA4(x0.z, pfe[q][2], a0); FMA4(x1.z, pfe[q][2], a1);
        FMA4(x0.w, pfe[q][3], a0); FMA4(x1.w, pfe[q][3], a1);
      }
      // streamed K-row quads 9..31 (rows 36..127)
      #pragma unroll 8
      for (int k4 = 9; k4 < 32; ++k4) {
        const float4 x0 = *(const float4*)&xb0[k4 << 2];
        const float4 x1 = *(const float4*)&xb1[k4 << 2];
        float4 w;
        w = *(const float4*)(wpB + (size_t)(k4 * 4 + 0) * 512); FMA4(x0.x, w, a0); FMA4(x1.x, w, a1);
        w = *(const float4*)(wpB + (size_t)(k4 * 4 + 1) * 512); FMA4(x0.y, w, a0); FMA4(x1.y, w, a1);
        w = *(const float4*)(wpB + (size_t)(k4 * 4 + 2) * 512); FMA4(x0.z, w, a0); FMA4(x1.z, w, a1);
        w = *(const float4*)(wpB + (size_t)(k4 * 4 + 3) * 512); FMA4(x0.w, w, a0); FMA4(x1.w, w, a1);
      }
      *(float4*)&gS[0][kq][col4] = a0;
      *(float4*)&gS[1][kq][col4] = a1;
    }
    __syncthreads();

    // C: LSTM + logits + decision (one wave per row, 2 cells/lane)
    if (tid < 128) {
      const int row = tid >> 6, l = tid & 63;
      double p0 = 0.0, p1 = 0.0;
      #pragma unroll
      for (int j = 0; j < 2; ++j) {
        const int cell = l + (j << 6);
        float gi = tbS[cell], gf = tbS[128 + cell], go = tbS[256 + cell], gg = tbS[384 + cell];
        #pragma unroll
        for (int k = 0; k < 4; ++k) {
          gi += gS[row][k][cell];
          gf += gS[row][k][128 + cell];
          go += gS[row][k][256 + cell];
          gg += gS[row][k][384 + cell];
        }
        const float cv = sigf(gf) * cS[row][cell] + sigf(gi) * tanhf(gg);
        const float hv = sigf(go) * tanhf(cv);
        cS[row][cell] = cv; hS[row][cell] = hv;
        p0 += (double)hv * (double)twS[2 * cell];
        p1 += (double)hv * (double)twS[2 * cell + 1];
      }
      #pragma unroll
      for (int off = 32; off; off >>= 1) { p0 += __shfl_down(p0, off); p1 += __shfl_down(p1, off); }
      if (l == 0) {
        const int qi0 = scalS[row][0], bp0 = scalS[row][1], us = scalS[row][2], len = scalS[row][3];
        float l0 = (float)p0 + twbS[0];
        float l1 = (float)p1 + twbS[1];
        if (us == 0)  l0 += NEGF;
        if (qi0 <= 0) l1 += NEGF;
        const int trans = (l1 > l0) ? 1 : 0;
        const float m = fmaxf(l0, l1);
        const float sh0 = l0 - m, sh1 = l1 - m;
        const float lse = logf(expf(sh0) + expf(sh1));
        const float lp0 = sh0 - lse, lp1 = sh1 - lse;
        const float logp = trans ? lp1 : lp0;
        const float pe0 = expf(lp0), pe1 = expf(lp1);
        const float ent = -((pe0 > 0.f ? pe0 * lp0 : 0.f) + (pe1 > 0.f ? pe1 * lp1 : 0.f));
        const int is_s = trans ? 0 : 1;
        const int is_r = trans;
        int qi2 = qi0 + is_s - is_r; qi2 = (qi2 < -1) ? -1 : ((qi2 > 31) ? 31 : qi2);
        int bp2 = bp0 + is_s; if (bp2 > 31) bp2 = 31;
        scalS[row][0] = qi2; scalS[row][1] = bp2; scalS[row][2] = us - is_s; scalS[row][4] = is_r;
        const int bb = b0 + row;
        const int done = (t >= 2 * len - 1);
        out[OUT_TRANS + bb * SS + t] = done ? 2.0f : (float)trans;
        out[OUT_LP + bb * SS + t]    = done ? 0.0f : logp;
        out[OUT_ENT + bb * SS + t]   = done ? 0.0f : ent;
      }
    }
    __syncthreads();

    // D: issue next-step weight prefetch (quads 3..5), then emb prefetch / comp
    #pragma unroll
    for (int q = 0; q < 3; ++q)
      #pragma unroll
      for (int r = 0; r < 4; ++r)
        pfd[q][r] = *(const float4*)(wpB + (size_t)((q + 3) * 4 + r) * 512);
    if (du < 0) {
      const int row = tid >> 6, c2 = (tid & 63) << 1;
      const int tok = msgS[row][scalS[row][1]];
      const float2 ea = *(const float2*)&embedding[(size_t)tok * 256 + c2];
      const float2 eb = *(const float2*)&embedding[(size_t)tok * 256 + 128 + c2];
      *(float2*)&topS[row][c2] = ea;
      *(float2*)&e1S[row][c2] = eb;
    } else if (scalS[0][4] | scalS[1][4]) {
      float4 a0 = {0.f, 0.f, 0.f, 0.f}, a1 = {0.f, 0.f, 0.f, 0.f};
      const float* hp0 = &hS[0][kqd << 5];
      const float* hp1 = &hS[1][kqd << 5];
      #pragma unroll 2
      for (int q = 0; q < 8; ++q) {
        const float4 h0 = *(const float4*)&hp0[q << 2];
        const float4 h1 = *(const float4*)&hp1[q << 2];
        float4 w;
        w = *(const float4*)(wpD + (size_t)(q * 4 + 0) * 640); FMA4(h0.x, w, a0); FMA4(h1.x, w, a1);
        w = *(const float4*)(wpD + (size_t)(q * 4 + 1) * 640); FMA4(h0.y, w, a0); FMA4(h1.y, w, a1);
        w = *(const float4*)(wpD + (size_t)(q * 4 + 2) * 640); FMA4(h0.z, w, a0); FMA4(h1.z, w, a1);
        w = *(const float4*)(wpD + (size_t)(q * 4 + 3) * 640); FMA4(h0.w, w, a0); FMA4(h1.w, w, a1);
      }
      *(float4*)&compS[0][kqd][pcol4] = a0;
      *(float4*)&compS[1][kqd][pcol4] = a1;
    }
    __syncthreads();

    // E: issue next-step weight prefetch (quads 6..8), then compose/shift + LN
    #pragma unroll
    for (int q = 0; q < 3; ++q)
      #pragma unroll
      for (int r = 0; r < 4; ++r)
        pfe[q][r] = *(const float4*)(wpB + (size_t)((q + 6) * 4 + r) * 512);
    if (tid < 128) {
      const int row = tid >> 6, l = tid & 63;
      float va0, va1, vb0, vb1;
      if (scalS[row][4]) {
        #pragma unroll
        for (int half = 0; half < 2; ++half) {
          const int c = l + (half << 6);
          float ci = cbS[c], co = cbS[128 + c], cg = cbS[256 + c];
          #pragma unroll
          for (int k = 0; k < 4; ++k) {
            ci += compS[row][k][c];
            co += compS[row][k][128 + c];
            cg += compS[row][k][256 + c];
          }
          const float cc = sigf(ci) * tanhf(cg);
          const float ch = sigf(co) * cc;
          if (half == 0) { va0 = ch; va1 = cc; } else { vb0 = ch; vb1 = cc; }
        }
      } else {
        va0 = topS[row][l];      va1 = e1S[row][l];
        vb0 = topS[row][l + 64]; vb1 = e1S[row][l + 64];
      }
      double sm = (double)va0 + (double)va1 + (double)vb0 + (double)vb1;
      double sq = (double)va0 * va0 + (double)va1 * va1 + (double)vb0 * vb0 + (double)vb1 * vb1;
      #pragma unroll
      for (int off = 32; off; off >>= 1) { sm += __shfl_xor(sm, off); sq += __shfl_xor(sq, off); }
      const double mu_d = sm * (1.0 / 256.0);
      const double ex2  = sq * (1.0 / 256.0);
      const float muf = (float)mu_d;
      const float inv = 1.0f / sqrtf((float)(ex2 - mu_d * mu_d) + 1e-5f);
      float* tp = out + OUT_THIN + ((size_t)(b0 + row) * SS + t) * 256;
      const float oa0 = (va0 - muf) * inv * lgS[l] + lbS[l];
      const float ob0 = (vb0 - muf) * inv * lgS[l + 64] + lbS[l + 64];
      tp[l]        = oa0;
      tp[l + 64]   = ob0;
      tp[128 + l]      = (va1 - muf) * inv * lgS[128 + l] + lbS[128 + l];
      tp[128 + l + 64] = (vb1 - muf) * inv * lgS[128 + l + 64] + lbS[128 + l + 64];
      thinL[row][t & 1][l]      = oa0;
      thinL[row][t & 1][l + 64] = ob0;
    }
    __syncthreads();
  }

  // epilogue: hidden = thin[2*len-2][:128]
  if (tid < 256) {
    const int row = tid >> 7, c = tid & 127;
    const int len = scalS[row][3];
    const int bb = b0 + row;
    out[(size_t)bb * 128 + c] = out[OUT_THIN + ((size_t)bb * SS + (2 * len - 2)) * 256 + c];
  }
}

extern "C" void kernel_launch(void* const* d_in, const int* in_sizes, int n_in,
                              void* d_out, int out_size, void* d_ws, size_t ws_size,
                              hipStream_t stream) {
  const int*   messages  = (const int*)d_in[0];
  const float* embedding = (const float*)d_in[1];
  const float* track_W   = (const float*)d_in[2];
  const float* track_b   = (const float*)d_in[3];
  const float* trans_W   = (const float*)d_in[4];
  const float* trans_b   = (const float*)d_in[5];
  const float* comp_W    = (const float*)d_in[6];
  const float* comp_b    = (const float*)d_in[7];
  const float* ln_g      = (const float*)d_in[8];
  const float* ln_b      = (const float*)d_in[9];
  float* out = (float*)d_out;
  (void)in_sizes; (void)n_in; (void)out_size; (void)d_ws; (void)ws_size;

  spinn_kernel<<<dim3(256), dim3(512), 0, stream>>>(
      messages, embedding, track_W, track_b, trans_W, trans_b,
      comp_W, comp_b, ln_g, ln_b, out);
}

// Round 10
// 665.710 us; speedup vs baseline: 1.3861x; 1.0814x over previous
//
#include <hip/hip_runtime.h>
#include <math.h>

// Sizes: B=512, L=32, D=128, DT=128, S=63
#define SS 63
#define NEGF (-3.4028234663852886e+38f)

// d_out layout (floats): hidden(512*128) | thin(512*63*256) | trans(512*63) | lp | ent
#define OUT_THIN   65536
#define OUT_TRANS  8323072
#define OUT_LP     8355328
#define OUT_ENT    8387584

#define WC 12   // track_W rows per kq-group cached in LDS (4*12*512*4B = 96 KB)

__device__ __forceinline__ float sigf(float x) { return 1.0f / (1.0f + expf(-x)); }

// NOTE: param names must not collide with .x/.y/.z/.w member tokens (macro capture!)
#define FMA4(S, W, A) { (A).x = fmaf((S), (W).x, (A).x); (A).y = fmaf((S), (W).y, (A).y); \
                        (A).z = fmaf((S), (W).z, (A).z); (A).w = fmaf((S), (W).w, (A).w); }

// ===== FINAL: exact round-7 structure (666 us verified) =====
// 256 blocks x 2 rows x 512 threads (8 waves) — L2-resident regime (13 MB fetch).
// 48 of 512 track_W K-rows (96 KB) live in LDS for the whole scan; the rest
// stream from L2 each step, shared across both rows in registers.
// Phase B streams ~1.04 MB/step/CU at ~116 GB/s/CU ≈ 86% of the per-CU L2 share —
// the binding constraint. Structure forced: 512 rows / 256 CUs + sequential scan.
// Refuted by experiment (do not retry):
//  r4: long-lived register W-cache -> hipcc spill, GBs of scratch traffic
//  r5: launch_bounds waves/EU cap -> VGPR<=64 -> spill -> 338 MB fetch
//  r6: K-loop rotation -> +3.3M bank conflicts, no L2 gain
//  r8: stream unroll 14 / WC 14 -> -28% (load bursts stall)
//  r9: cross-phase register prefetch -> -8% (VGPR pressure, port contention)
// Verified identities: s1=thin[t-1], s2=thin[t-2]; compose st1/st2 are zero rows ->
// comp needs only K-rows 128..255 and the ci/co/cg columns (packed 384).
__global__ __launch_bounds__(512, 2) void spinn_kernel(
    const int* __restrict__ messages,
    const float* __restrict__ embedding,
    const float* __restrict__ track_W,
    const float* __restrict__ track_b,
    const float* __restrict__ trans_W,
    const float* __restrict__ trans_b,
    const float* __restrict__ comp_W,
    const float* __restrict__ comp_b,
    const float* __restrict__ ln_g,
    const float* __restrict__ ln_b,
    float* __restrict__ out)
{
  __shared__ __align__(16) float wS[4][WC][512];    // cached track_W rows (96 KB)
  __shared__ __align__(16) float gS[2][4][512];     // track partials [row][kq][col]
  __shared__ __align__(16) float compS[2][4][384];  // comp partials [row][kq][packed ci|co|cg]
  __shared__ __align__(16) float thinL[2][2][128];  // rolling thin[t-1], thin[t-2] first halves
  __shared__ __align__(16) float topS[2][128];      // emb[msg[bp]] first half
  __shared__ __align__(16) float e1S[2][128];       // emb[msg[bp]] second half
  __shared__ __align__(16) float hS[2][128];
  __shared__ __align__(16) float cS[2][128];
  __shared__ float tbS[512];                        // track_b
  __shared__ float cbS[384];                        // comp_b packed [ci|co|cg]
  __shared__ float lgS[256], lbS[256];
  __shared__ float twS[256];                        // trans_W
  __shared__ float twbS[2];                         // trans_b
  __shared__ int   msgS[2][32];
  __shared__ int   scalS[2][8];                     // 0:qi 1:bp 2:us 3:len 4:is_r
  __shared__ double redP[8][2];                     // prologue LN stats

  const int tid = (int)threadIdx.x;
  const int b0 = (int)blockIdx.x * 2;

  // ---- per-thread invariants ----
  // phase B (track GEMV): kq in [0,4) picks 128 K-rows (= x segment); col4: 4 cols
  const int kq   = tid >> 7;
  const int col4 = (tid & 127) << 2;
  const float* const wpB = track_W + (size_t)(kq << 7) * 512 + col4;
  // phase D (comp GEMV): 384 threads (tid in [128,512)): g=gate, kqd: 32 K-rows
  const int du = tid - 128;
  int kqd = 0, pcol4 = 0, real4 = 0, gD = 0;
  if (du >= 0) {
    gD = du >> 7;                               // 0:ci 1:co 2:cg
    const int w7 = du & 127;
    kqd = w7 >> 5;                              // [0,4) -> 32 K-rows each
    pcol4 = (gD << 7) + ((w7 & 31) << 2);       // packed col [0,384)
    const int colbase = (gD == 0) ? 0 : ((gD == 1) ? 384 : 512);
    real4 = colbase + ((w7 & 31) << 2);
  }
  const float* const wpD = comp_W + (size_t)(128 + (kqd << 5)) * 640 + real4;

  // ---- P0: stage constants + W cache ----
  if (tid < 64) msgS[tid >> 5][tid & 31] = messages[(b0 + (tid >> 5)) * 32 + (tid & 31)];
  if (tid < 2) twbS[tid] = trans_b[tid];
  tbS[tid] = track_b[tid];
  if (tid < 384) {
    const int g = tid >> 7;
    const int off = (g == 0) ? 0 : ((g == 1) ? 384 : 512);
    cbS[tid] = comp_b[off + (tid & 127)];
  }
  if (tid < 256) {
    lgS[tid] = ln_g[tid]; lbS[tid] = ln_b[tid]; twS[tid] = trans_W[tid];
    hS[tid >> 7][tid & 127] = 0.0f; cS[tid >> 7][tid & 127] = 0.0f;
  }
  // stage first WC rows of this thread's kq-group (same mapping as B reads)
  #pragma unroll
  for (int r = 0; r < WC; ++r)
    *(float4*)&wS[kq][r][col4] = *(const float4*)(wpB + (size_t)r * 512);
  __syncthreads();

  // ---- P1: scalar init + topS for t=2 ----
  if (tid < 2) {
    const int r = tid;
    int len = 32;
    for (int i = 0; i < 32; ++i) if (msgS[r][i] == 0) { len = i + 1; break; }
    scalS[r][0] = 1; scalS[r][1] = 2; scalS[r][2] = len - 2; scalS[r][3] = len; scalS[r][4] = 0;
    const int bb = b0 + r;
    #pragma unroll
    for (int s = 0; s < 2; ++s) {
      const int done = (s >= 2 * len - 1);
      out[OUT_TRANS + bb * SS + s] = done ? 2.0f : 0.0f;
      out[OUT_LP + bb * SS + s] = 0.0f;
      out[OUT_ENT + bb * SS + s] = 0.0f;
    }
  }
  if (tid >= 256) {
    const int u = tid - 256;
    if (u < 256) topS[u >> 7][u & 127] = embedding[(size_t)msgS[u >> 7][2] * 256 + (u & 127)];
  }
  __syncthreads();

  // ---- P2: thin[0], thin[1] = LN(emb[msg[0/1]]) (512 threads: s=tid>>8) ----
  {
    const int s = tid >> 8, row = (tid >> 7) & 1, c = tid & 127;
    const int tok = msgS[row][s];
    const float v0 = embedding[(size_t)tok * 256 + c];
    const float v1 = embedding[(size_t)tok * 256 + 128 + c];
    double sm = (double)v0 + (double)v1;
    double sq = (double)v0 * v0 + (double)v1 * v1;
    #pragma unroll
    for (int off = 32; off; off >>= 1) { sm += __shfl_down(sm, off); sq += __shfl_down(sq, off); }
    if ((tid & 63) == 0) { redP[tid >> 6][0] = sm; redP[tid >> 6][1] = sq; }
    __syncthreads();
    const int wb = (tid >> 7) << 1;
    const double mu_d = (redP[wb][0] + redP[wb + 1][0]) * (1.0 / 256.0);
    const double ex2  = (redP[wb][1] + redP[wb + 1][1]) * (1.0 / 256.0);
    const float muf = (float)mu_d;
    const float inv = 1.0f / sqrtf((float)(ex2 - mu_d * mu_d) + 1e-5f);
    const float o0 = (v0 - muf) * inv * lgS[c] + lbS[c];
    const float o1 = (v1 - muf) * inv * lgS[128 + c] + lbS[128 + c];
    float* tp = out + OUT_THIN + ((size_t)(b0 + row) * SS + s) * 256;
    tp[c] = o0; tp[128 + c] = o1;
    thinL[row][s][c] = o0;
    __syncthreads();
  }

  // ---------------- scan: t = 2 .. 62 ----------------
  for (int t = 2; t < SS; ++t) {
    // B: gates partials (all 8 waves); rows 0..11 LDS, 12..127 streamed from L2
    {
      const float *xb0, *xb1;
      if (kq == 0)      { xb0 = topS[0];               xb1 = topS[1]; }
      else if (kq == 1) { xb0 = thinL[0][(t + 1) & 1]; xb1 = thinL[1][(t + 1) & 1]; }
      else if (kq == 2) { xb0 = thinL[0][t & 1];       xb1 = thinL[1][t & 1]; }
      else              { xb0 = hS[0];                 xb1 = hS[1]; }
      float4 a0 = {0.f, 0.f, 0.f, 0.f}, a1 = {0.f, 0.f, 0.f, 0.f};
      // cached K-rows (quads 0..2 from LDS), same accumulation order
      #pragma unroll
      for (int k4 = 0; k4 < 3; ++k4) {
        const float4 x0 = *(const float4*)&xb0[k4 << 2];
        const float4 x1 = *(const float4*)&xb1[k4 << 2];
        float4 w;
        w = *(const float4*)&wS[kq][k4 * 4 + 0][col4]; FMA4(x0.x, w, a0); FMA4(x1.x, w, a1);
        w = *(const float4*)&wS[kq][k4 * 4 + 1][col4]; FMA4(x0.y, w, a0); FMA4(x1.y, w, a1);
        w = *(const float4*)&wS[kq][k4 * 4 + 2][col4]; FMA4(x0.z, w, a0); FMA4(x1.z, w, a1);
        w = *(const float4*)&wS[kq][k4 * 4 + 3][col4]; FMA4(x0.w, w, a0); FMA4(x1.w, w, a1);
      }
      // streamed K-rows 12..127
      #pragma unroll 8
      for (int k4 = WC / 4; k4 < 32; ++k4) {
        const float4 x0 = *(const float4*)&xb0[k4 << 2];
        const float4 x1 = *(const float4*)&xb1[k4 << 2];
        float4 w;
        w = *(const float4*)(wpB + (size_t)(k4 * 4 + 0) * 512); FMA4(x0.x, w, a0); FMA4(x1.x, w, a1);
        w = *(const float4*)(wpB + (size_t)(k4 * 4 + 1) * 512); FMA4(x0.y, w, a0); FMA4(x1.y, w, a1);
        w = *(const float4*)(wpB + (size_t)(k4 * 4 + 2) * 512); FMA4(x0.z, w, a0); FMA4(x1.z, w, a1);
        w = *(const float4*)(wpB + (size_t)(k4 * 4 + 3) * 512); FMA4(x0.w, w, a0); FMA4(x1.w, w, a1);
      }
      *(float4*)&gS[0][kq][col4] = a0;
      *(float4*)&gS[1][kq][col4] = a1;
    }
    __syncthreads();

    // C: LSTM + logits + decision (one wave per row, 2 cells/lane)
    if (tid < 128) {
      const int row = tid >> 6, l = tid & 63;
      double p0 = 0.0, p1 = 0.0;
      #pragma unroll
      for (int j = 0; j < 2; ++j) {
        const int cell = l + (j << 6);
        float gi = tbS[cell], gf = tbS[128 + cell], go = tbS[256 + cell], gg = tbS[384 + cell];
        #pragma unroll
        for (int k = 0; k < 4; ++k) {
          gi += gS[row][k][cell];
          gf += gS[row][k][128 + cell];
          go += gS[row][k][256 + cell];
          gg += gS[row][k][384 + cell];
        }
        const float cv = sigf(gf) * cS[row][cell] + sigf(gi) * tanhf(gg);
        const float hv = sigf(go) * tanhf(cv);
        cS[row][cell] = cv; hS[row][cell] = hv;
        p0 += (double)hv * (double)twS[2 * cell];
        p1 += (double)hv * (double)twS[2 * cell + 1];
      }
      #pragma unroll
      for (int off = 32; off; off >>= 1) { p0 += __shfl_down(p0, off); p1 += __shfl_down(p1, off); }
      if (l == 0) {
        const int qi0 = scalS[row][0], bp0 = scalS[row][1], us = scalS[row][2], len = scalS[row][3];
        float l0 = (float)p0 + twbS[0];
        float l1 = (float)p1 + twbS[1];
        if (us == 0)  l0 += NEGF;
        if (qi0 <= 0) l1 += NEGF;
        const int trans = (l1 > l0) ? 1 : 0;
        const float m = fmaxf(l0, l1);
        const float sh0 = l0 - m, sh1 = l1 - m;
        const float lse = logf(expf(sh0) + expf(sh1));
        const float lp0 = sh0 - lse, lp1 = sh1 - lse;
        const float logp = trans ? lp1 : lp0;
        const float pe0 = expf(lp0), pe1 = expf(lp1);
        const float ent = -((pe0 > 0.f ? pe0 * lp0 : 0.f) + (pe1 > 0.f ? pe1 * lp1 : 0.f));
        const int is_s = trans ? 0 : 1;
        const int is_r = trans;
        int qi2 = qi0 + is_s - is_r; qi2 = (qi2 < -1) ? -1 : ((qi2 > 31) ? 31 : qi2);
        int bp2 = bp0 + is_s; if (bp2 > 31) bp2 = 31;
        scalS[row][0] = qi2; scalS[row][1] = bp2; scalS[row][2] = us - is_s; scalS[row][4] = is_r;
        const int bb = b0 + row;
        const int done = (t >= 2 * len - 1);
        out[OUT_TRANS + bb * SS + t] = done ? 2.0f : (float)trans;
        out[OUT_LP + bb * SS + t]    = done ? 0.0f : logp;
        out[OUT_ENT + bb * SS + t]   = done ? 0.0f : ent;
      }
    }
    __syncthreads();

    // D: embedding prefetch (tid<128) || comp matvec (tid>=128, only if some row reduced)
    if (du < 0) {
      const int row = tid >> 6, c2 = (tid & 63) << 1;
      const int tok = msgS[row][scalS[row][1]];
      const float2 ea = *(const float2*)&embedding[(size_t)tok * 256 + c2];
      const float2 eb = *(const float2*)&embedding[(size_t)tok * 256 + 128 + c2];
      *(float2*)&topS[row][c2] = ea;
      *(float2*)&e1S[row][c2] = eb;
    } else if (scalS[0][4] | scalS[1][4]) {
      float4 a0 = {0.f, 0.f, 0.f, 0.f}, a1 = {0.f, 0.f, 0.f, 0.f};
      const float* hp0 = &hS[0][kqd << 5];
      const float* hp1 = &hS[1][kqd << 5];
      #pragma unroll 2
      for (int q = 0; q < 8; ++q) {
        const float4 h0 = *(const float4*)&hp0[q << 2];
        const float4 h1 = *(const float4*)&hp1[q << 2];
        float4 w;
        w = *(const float4*)(wpD + (size_t)(q * 4 + 0) * 640); FMA4(h0.x, w, a0); FMA4(h1.x, w, a1);
        w = *(const float4*)(wpD + (size_t)(q * 4 + 1) * 640); FMA4(h0.y, w, a0); FMA4(h1.y, w, a1);
        w = *(const float4*)(wpD + (size_t)(q * 4 + 2) * 640); FMA4(h0.z, w, a0); FMA4(h1.z, w, a1);
        w = *(const float4*)(wpD + (size_t)(q * 4 + 3) * 640); FMA4(h0.w, w, a0); FMA4(h1.w, w, a1);
      }
      *(float4*)&compS[0][kqd][pcol4] = a0;
      *(float4*)&compS[1][kqd][pcol4] = a1;
    }
    __syncthreads();

    // E: compose/shift + LN, one wave per row, lanes cover c=l and c=l+64
    if (tid < 128) {
      const int row = tid >> 6, l = tid & 63;
      float va0, va1, vb0, vb1;
      if (scalS[row][4]) {
        #pragma unroll
        for (int half = 0; half < 2; ++half) {
          const int c = l + (half << 6);
          float ci = cbS[c], co = cbS[128 + c], cg = cbS[256 + c];
          #pragma unroll
          for (int k = 0; k < 4; ++k) {
            ci += compS[row][k][c];
            co += compS[row][k][128 + c];
            cg += compS[row][k][256 + c];
          }
          const float cc = sigf(ci) * tanhf(cg);
          const float ch = sigf(co) * cc;
          if (half == 0) { va0 = ch; va1 = cc; } else { vb0 = ch; vb1 = cc; }
        }
      } else {
        va0 = topS[row][l];      va1 = e1S[row][l];
        vb0 = topS[row][l + 64]; vb1 = e1S[row][l + 64];
      }
      double sm = (double)va0 + (double)va1 + (double)vb0 + (double)vb1;
      double sq = (double)va0 * va0 + (double)va1 * va1 + (double)vb0 * vb0 + (double)vb1 * vb1;
      #pragma unroll
      for (int off = 32; off; off >>= 1) { sm += __shfl_xor(sm, off); sq += __shfl_xor(sq, off); }
      const double mu_d = sm * (1.0 / 256.0);
      const double ex2  = sq * (1.0 / 256.0);
      const float muf = (float)mu_d;
      const float inv = 1.0f / sqrtf((float)(ex2 - mu_d * mu_d) + 1e-5f);
      float* tp = out + OUT_THIN + ((size_t)(b0 + row) * SS + t) * 256;
      const float oa0 = (va0 - muf) * inv * lgS[l] + lbS[l];
      const float ob0 = (vb0 - muf) * inv * lgS[l + 64] + lbS[l + 64];
      tp[l]        = oa0;
      tp[l + 64]   = ob0;
      tp[128 + l]      = (va1 - muf) * inv * lgS[128 + l] + lbS[128 + l];
      tp[128 + l + 64] = (vb1 - muf) * inv * lgS[128 + l + 64] + lbS[128 + l + 64];
      thinL[row][t & 1][l]      = oa0;
      thinL[row][t & 1][l + 64] = ob0;
    }
    __syncthreads();
  }

  // epilogue: hidden = thin[2*len-2][:128]
  if (tid < 256) {
    const int row = tid >> 7, c = tid & 127;
    const int len = scalS[row][3];
    const int bb = b0 + row;
    out[(size_t)bb * 128 + c] = out[OUT_THIN + ((size_t)bb * SS + (2 * len - 2)) * 256 + c];
  }
}

extern "C" void kernel_launch(void* const* d_in, const int* in_sizes, int n_in,
                              void* d_out, int out_size, void* d_ws, size_t ws_size,
                              hipStream_t stream) {
  const int*   messages  = (const int*)d_in[0];
  const float* embedding = (const float*)d_in[1];
  const float* track_W   = (const float*)d_in[2];
  const float* track_b   = (const float*)d_in[3];
  const float* trans_W   = (const float*)d_in[4];
  const float* trans_b   = (const float*)d_in[5];
  const float* comp_W    = (const float*)d_in[6];
  const float* comp_b    = (const float*)d_in[7];
  const float* ln_g      = (const float*)d_in[8];
  const float* ln_b      = (const float*)d_in[9];
  float* out = (float*)d_out;
  (void)in_sizes; (void)n_in; (void)out_size; (void)d_ws; (void)ws_size;

  spinn_kernel<<<dim3(256), dim3(512), 0, stream>>>(
      messages, embedding, track_W, track_b, trans_W, trans_b,
      comp_W, comp_b, ln_g, ln_b, out);
}